// Round 10
// baseline (42.761 us; speedup 1.0000x reference)
//
#include <hip/hip_runtime.h>
#include <hip/hip_bf16.h>

typedef unsigned short u16;
typedef unsigned int   u32;
typedef __attribute__((ext_vector_type(8))) short short8;
typedef __attribute__((ext_vector_type(4))) short short4v;
typedef __attribute__((ext_vector_type(4))) float f32x4;

#define BATCH 2
#define CCH   128
#define HH    96
#define WW    96
#define HWSZ  9216
#define HEADS 8
#define HD    16
#define GROUPS 32
#define EPSV  1e-6f

#if defined(__has_builtin)
#if __has_builtin(__builtin_amdgcn_mfma_f32_16x16x16bf16_1k)
#define HAVE_MFMA16 1
#endif
#endif

// fp32 -> bf16 RNE via hardware convert
static __device__ __forceinline__ u16 f2bf(float f) {
    return __builtin_bit_cast(u16, (__bf16)f);
}
static __device__ __forceinline__ u32 pk2(float a, float b) {
    return (u32)f2bf(a) | ((u32)f2bf(b) << 16);
}
static __device__ __forceinline__ short8 mk8(u32 a, u32 b, u32 c, u32 d) {
    union { short8 v; u32 w[4]; } u; u.w[0]=a; u.w[1]=b; u.w[2]=c; u.w[3]=d; return u.v;
}
static __device__ __forceinline__ short4v mk4(u32 a, u32 b) {
    union { short4v v; u32 w[2]; } u; u.w[0]=a; u.w[1]=b; return u.v;
}

// ---------------------------------------------------------------------------
// Fused: GN partial stats (blocks 0..255) + weight packing (blocks 256..287).
// ---------------------------------------------------------------------------
__global__ __launch_bounds__(256) void gn_wpack(const float* __restrict__ x,
                                                float* __restrict__ partial,
                                                const float* __restrict__ qkv_w,
                                                const float* __restrict__ proj_w,
                                                u16* __restrict__ Wq, u16* __restrict__ Wp) {
    if (blockIdx.x < 256) {
        const int bq = blockIdx.x;
        const float4* base = (const float4*)(x + (size_t)bq * 9216);
        float s = 0.f, ss = 0.f;
        #pragma unroll
        for (int i = 0; i < 9; ++i) {
            float4 v = base[threadIdx.x + i * 256];
            s  += v.x + v.y + v.z + v.w;
            ss += v.x * v.x + v.y * v.y + v.z * v.z + v.w * v.w;
        }
        #pragma unroll
        for (int off = 32; off > 0; off >>= 1) {
            s  += __shfl_down(s, off);
            ss += __shfl_down(ss, off);
        }
        __shared__ float rs[4], rss[4];
        const int wid = threadIdx.x >> 6, lane = threadIdx.x & 63;
        if (lane == 0) { rs[wid] = s; rss[wid] = ss; }
        __syncthreads();
        if (threadIdx.x == 0) {
            partial[2 * bq]     = rs[0] + rs[1] + rs[2] + rs[3];
            partial[2 * bq + 1] = rss[0] + rss[1] + rss[2] + rss[3];
        }
    } else {
        const int t = (blockIdx.x - 256) * 256 + threadIdx.x;
        if (t < 16 * 384) {
            int cb = t / 384, o = t % 384;
            u16 pk[8];
            #pragma unroll
            for (int j = 0; j < 8; ++j) pk[j] = f2bf(qkv_w[o * 128 + cb * 8 + j]);
            uint4 r;
            r.x = (u32)pk[0] | ((u32)pk[1] << 16); r.y = (u32)pk[2] | ((u32)pk[3] << 16);
            r.z = (u32)pk[4] | ((u32)pk[5] << 16); r.w = (u32)pk[6] | ((u32)pk[7] << 16);
            *(uint4*)(Wq + (size_t)t * 8) = r;
        } else if (t < 16 * 384 + 16 * 128) {
            int i = t - 16 * 384;
            int cb = i / 128, o = i % 128;
            u16 pk[8];
            #pragma unroll
            for (int j = 0; j < 8; ++j) pk[j] = f2bf(proj_w[o * 128 + cb * 8 + j]);
            uint4 r;
            r.x = (u32)pk[0] | ((u32)pk[1] << 16); r.y = (u32)pk[2] | ((u32)pk[3] << 16);
            r.z = (u32)pk[4] | ((u32)pk[5] << 16); r.w = (u32)pk[6] | ((u32)pk[7] << 16);
            *(uint4*)(Wp + (size_t)i * 8) = r;
        }
    }
}

// ---------------------------------------------------------------------------
// QKV GEMM fused with GroupNorm-normalize staging (round-9 proven).
// ---------------------------------------------------------------------------
__global__ __launch_bounds__(256) void qkv_fused(const float* __restrict__ x,
                                                 const float* __restrict__ partial,
                                                 const float* __restrict__ gamma,
                                                 const float* __restrict__ beta,
                                                 const u16* __restrict__ Wq,
                                                 const float* __restrict__ qkv_b,
                                                 u16* __restrict__ qkvp) {
    __shared__ float scale[CCH], shift[CCH];
    __shared__ u16 Xt[16 * 128 * 8];   // 32 KB
    const int t = threadIdx.x;
    const int pph = blockIdx.x;                  // 0..431
    const int L = (pph & 7) * 54 + (pph >> 3);   // chunk swizzle (432 = 8*54)
    const int b = L / 216;
    const int r = L % 216;
    const int pt = r / 3, ot = r % 3;

    if (t < CCH) {
        const int c = t, g = c >> 2, bg = b * GROUPS + g;
        float S = 0.f, SS = 0.f;
        #pragma unroll
        for (int q = 0; q < 4; ++q) {
            S  += partial[2 * (bg * 4 + q)];
            SS += partial[2 * (bg * 4 + q) + 1];
        }
        const float mean = S * (1.f / 36864.f);
        const float rstd = rsqrtf(SS * (1.f / 36864.f) - mean * mean + EPSV);
        const float sc = rstd * gamma[c];
        scale[c] = sc;
        shift[c] = beta[c] - mean * sc;
    }
    __syncthreads();

    {
        const int px = t & 127, chh = t >> 7;
        const float* xb = x + (size_t)b * CCH * HWSZ + (size_t)pt * 128 + px;
        #pragma unroll
        for (int cbi = 0; cbi < 8; ++cbi) {
            const int cb = chh * 8 + cbi;
            u16 pk[8];
            #pragma unroll
            for (int j = 0; j < 8; ++j) {
                const int c = cb * 8 + j;
                pk[j] = f2bf(__builtin_fmaf(xb[(size_t)c * HWSZ], scale[c], shift[c]));
            }
            uint4 o;
            o.x = (u32)pk[0] | ((u32)pk[1] << 16);
            o.y = (u32)pk[2] | ((u32)pk[3] << 16);
            o.z = (u32)pk[4] | ((u32)pk[5] << 16);
            o.w = (u32)pk[6] | ((u32)pk[7] << 16);
            *(uint4*)&Xt[((size_t)cb * 128 + px) * 8] = o;
        }
    }
    __syncthreads();

    const int l = t & 63, w = t >> 6;
    const int OB = ot * 128 + (w & 1) * 64;
    const int PL = (w >> 1) * 64;
    const int q = l >> 4, lo = l & 15;

    float bv[4][4];
    #pragma unroll
    for (int of = 0; of < 4; ++of)
        #pragma unroll
        for (int r2 = 0; r2 < 4; ++r2) bv[of][r2] = qkv_b[OB + of * 16 + q * 4 + r2];

    f32x4 acc[4][4] = {};
    #pragma unroll
    for (int ks = 0; ks < 4; ++ks) {
        const int cb = ks * 4 + q;
        short8 a[4];
        #pragma unroll
        for (int of = 0; of < 4; ++of)
            a[of] = *(const short8*)(Wq + ((size_t)cb * 384 + OB + of * 16 + lo) * 8);
        #pragma unroll
        for (int pf = 0; pf < 4; ++pf) {
            short8 bb = *(const short8*)&Xt[((size_t)cb * 128 + PL + pf * 16 + lo) * 8];
            #pragma unroll
            for (int of = 0; of < 4; ++of)
                acc[of][pf] = __builtin_amdgcn_mfma_f32_16x16x32_bf16(a[of], bb, acc[of][pf], 0, 0, 0);
        }
    }

    #pragma unroll
    for (int of = 0; of < 4; ++of) {
        const int plane = b * 24 + (OB >> 4) + of;
        #pragma unroll
        for (int pf = 0; pf < 4; ++pf) {
            const int p = pt * 128 + PL + pf * 16 + lo;
            uint2 pkt;
            pkt.x = pk2(acc[of][pf][0] + bv[of][0], acc[of][pf][1] + bv[of][1]);
            pkt.y = pk2(acc[of][pf][2] + bv[of][2], acc[of][pf][3] + bv[of][3]);
            *(uint2*)(qkvp + ((size_t)plane * HWSZ + p) * 16 + q * 4) = pkt;
        }
    }
}

// ---------------------------------------------------------------------------
// Proj GEMM: 288 blocks (round-8 proven).
// ---------------------------------------------------------------------------
__global__ __launch_bounds__(256) void proj_gemm(const u16* __restrict__ Wpk,
                                                 const u16* __restrict__ Xpk,
                                                 const float* __restrict__ bias,
                                                 float* __restrict__ out_f32) {
    const int bid = blockIdx.x;              // 0..287
    const int b = bid / 144, pt = bid % 144;
    const int l = threadIdx.x & 63, w = threadIdx.x >> 6;
    const int OB = (w & 1) * 64;
    const int PB = pt * 64 + (w >> 1) * 32;
    const int q = l >> 4, lo = l & 15;
    const u16* Xb = Xpk + (size_t)b * 16 * HWSZ * 8;

    float bv[4][4];
    #pragma unroll
    for (int of = 0; of < 4; ++of)
        #pragma unroll
        for (int r = 0; r < 4; ++r) bv[of][r] = bias[OB + of * 16 + q * 4 + r];

    f32x4 acc[4][2] = {};
    #pragma unroll
    for (int ks = 0; ks < 4; ++ks) {
        const int cb = ks * 4 + q;
        short8 a[4];
        #pragma unroll
        for (int of = 0; of < 4; ++of)
            a[of] = *(const short8*)(Wpk + ((size_t)cb * 128 + OB + of * 16 + lo) * 8);
        #pragma unroll
        for (int pf = 0; pf < 2; ++pf) {
            short8 bb = *(const short8*)(Xb + ((size_t)cb * HWSZ + PB + pf * 16 + lo) * 8);
            #pragma unroll
            for (int of = 0; of < 4; ++of)
                acc[of][pf] = __builtin_amdgcn_mfma_f32_16x16x32_bf16(a[of], bb, acc[of][pf], 0, 0, 0);
        }
    }

    #pragma unroll
    for (int of = 0; of < 4; ++of) {
        #pragma unroll
        for (int pf = 0; pf < 2; ++pf) {
            const int p = PB + pf * 16 + lo;
            #pragma unroll
            for (int r = 0; r < 4; ++r) {
                const int o = OB + of * 16 + q * 4 + r;
                out_f32[((size_t)(b * 128 + o)) * HWSZ + p] = acc[of][pf][r] + bv[of][r];
            }
        }
    }
}

// ---------------------------------------------------------------------------
// MFMA NATTEN v5. 16x16x16 bf16 MFMA (no dup/zero waste) with x32 fallback;
// exp2-folded softmax; V staged ch-major via paired b32 writes.
// Layouts (16x16x16): A[row=l&15][k=(l>>4)*4+j], B[k=(l>>4)*4+j][col=l&15],
// C/D[row=(l>>4)*4+r][col=l&15] — identical index math to the x32 version.
// ---------------------------------------------------------------------------
__global__ __launch_bounds__(384) void natten_mfma(const u16* __restrict__ qkv,
                                                   u16* __restrict__ attn_out) {
    __shared__ u16 Ks[13 * 64 * 16];   // 26 KB
    __shared__ u16 VsT[16 * 840];      // 26.3 KB
    const int tid = threadIdx.x;
    const int xh = blockIdx.x & 1, yb = blockIdx.x >> 1;
    const int h = blockIdx.y, b = blockIdx.z;
    const int ry0 = min(max(yb * 6 - 3, 0), 83);
    const int rx0 = xh * 32;

    for (int i = tid; i < 2496; i += 384) {
        if (i < 1664) {
            const int px = i >> 1, half = i & 1;
            const int row = px >> 6, col = px & 63;
            const u16* gp = qkv + ((size_t)(b * 24 + 8 + h) * HWSZ
                                 + (ry0 + row) * WW + rx0 + col) * 16 + half * 8;
            *(uint4*)&Ks[px * 16 + half * 8] = *(const uint4*)gp;
        } else {
            const int j2 = i - 1664;            // 0..831
            const int half = j2 & 1;
            const int px = (j2 >> 1) * 2;       // even pixel of the pair
            const int row = px >> 6, col = px & 63;   // col even <= 62
            const u16* gp = qkv + ((size_t)(b * 24 + 16 + h) * HWSZ
                                 + (ry0 + row) * WW + rx0 + col) * 16 + half * 8;
            const uint4 v0 = *(const uint4*)gp;
            const uint4 v1 = *(const uint4*)(gp + 16);
            const int ch0 = half * 8;
            u32* Wd = (u32*)VsT;
            const int wb = px >> 1;             // word offset within channel row
            Wd[(ch0 + 0) * 420 + wb] = (v0.x & 0xFFFFu) | (v1.x << 16);
            Wd[(ch0 + 1) * 420 + wb] = (v0.x >> 16)     | (v1.x & 0xFFFF0000u);
            Wd[(ch0 + 2) * 420 + wb] = (v0.y & 0xFFFFu) | (v1.y << 16);
            Wd[(ch0 + 3) * 420 + wb] = (v0.y >> 16)     | (v1.y & 0xFFFF0000u);
            Wd[(ch0 + 4) * 420 + wb] = (v0.z & 0xFFFFu) | (v1.z << 16);
            Wd[(ch0 + 5) * 420 + wb] = (v0.z >> 16)     | (v1.z & 0xFFFF0000u);
            Wd[(ch0 + 6) * 420 + wb] = (v0.w & 0xFFFFu) | (v1.w << 16);
            Wd[(ch0 + 7) * 420 + wb] = (v0.w >> 16)     | (v1.w & 0xFFFF0000u);
        }
    }
    __syncthreads();

    const int l = tid & 63, wv = tid >> 6;
    const int m = l & 15, q4 = l >> 4;
    const int yq = m >> 3, xq = m & 7;

    for (int j = 0; j < 3; ++j) {
        const int g = wv * 3 + j;
        const int gy = g / 6, gx = g % 6;
        const int y0g = yb * 6 + gy * 2, x0g = xh * 48 + gx * 8;
        const int yabs = y0g + yq, xabs = x0g + xq;
        const int sy = min(max(yabs - 3, 0), 88);
        const int sx = min(max(xabs - 3, 0), 88);
        const int dy0 = min(max(y0g - 3, 0), 88) - ry0;
        const int rd0 = dy0 - (sy - ry0);
        const int cx0 = (min(max(x0g - 3 - rx0, 0), 48)) & ~3;
        const int cd0 = cx0 + q4 * 4 - (sx - rx0);
        const int qpix = yabs * WW + xabs;

        const uint2 qw = *(const uint2*)(qkv + ((size_t)(b * 24 + h) * HWSZ + qpix) * 16 + q4 * 4);
#ifndef HAVE_MFMA16
        const short8 qb = mk8(qw.x, qw.y, 0u, 0u);
#endif

        const float NEGB = -1e30f;
        const float SC = 0.25f * 1.4426950408889634f;   // fold 1/sqrt(hd) and log2e
        float colb[4];
        #pragma unroll
        for (int r = 0; r < 4; ++r) colb[r] = ((u32)(cd0 + r) < 8u) ? 0.f : NEGB;

        float ev[9][4];
        float vs = 0.f;
        #pragma unroll
        for (int t = 0; t < 9; ++t) {
            const int trow = min(dy0 + t, 12);
            const uint2 kk = *(const uint2*)&Ks[(trow * 64 + cx0 + m) * 16 + q4 * 4];
#ifdef HAVE_MFMA16
            f32x4 lg = __builtin_amdgcn_mfma_f32_16x16x16bf16_1k(
                mk4(kk.x, kk.y), mk4(qw.x, qw.y), (f32x4){0.f, 0.f, 0.f, 0.f}, 0, 0, 0);
#else
            f32x4 lg = __builtin_amdgcn_mfma_f32_16x16x32_bf16(
                mk8(kk.x, kk.y, kk.x, kk.y), qb, (f32x4){0.f, 0.f, 0.f, 0.f}, 0, 0, 0);
#endif
            const float rb = ((u32)(t + rd0) < 8u) ? 0.f : NEGB;
            #pragma unroll
            for (int r = 0; r < 4; ++r) {
                const float e = exp2f(__builtin_fmaf(lg[r], SC, colb[r] + rb));
                ev[t][r] = e;
                vs += e;
            }
        }
        vs += __shfl_xor(vs, 16);
        vs += __shfl_xor(vs, 32);
        const float inv = 1.0f / vs;

        u32 pd0[9], pd1[9];
        #pragma unroll
        for (int t = 0; t < 9; ++t) {
            pd0[t] = pk2(ev[t][0], ev[t][1]);
            pd1[t] = pk2(ev[t][2], ev[t][3]);
        }

        f32x4 acc = {};
        #pragma unroll
        for (int t = 0; t < 9; ++t) {
            const int trow = min(dy0 + t, 12);
            const uint2 va = *(const uint2*)&VsT[m * 840 + trow * 64 + cx0 + q4 * 4];
#ifdef HAVE_MFMA16
            acc = __builtin_amdgcn_mfma_f32_16x16x16bf16_1k(
                mk4(va.x, va.y), mk4(pd0[t], pd1[t]), acc, 0, 0, 0);
#else
            acc = __builtin_amdgcn_mfma_f32_16x16x32_bf16(
                mk8(va.x, va.y, va.x, va.y), mk8(pd0[t], pd1[t], 0u, 0u), acc, 0, 0, 0);
#endif
        }

        uint2 od;
        od.x = pk2(acc[0] * inv, acc[1] * inv);
        od.y = pk2(acc[2] * inv, acc[3] * inv);
        *(uint2*)(attn_out + ((size_t)(b * 16 + h * 2 + (q4 >> 1)) * HWSZ + qpix) * 8
                  + (q4 & 1) * 4) = od;
    }
}

// ---------------------------------------------------------------------------
extern "C" void kernel_launch(void* const* d_in, const int* in_sizes, int n_in,
                              void* d_out, int out_size, void* d_ws, size_t ws_size,
                              hipStream_t stream) {
    const float* x      = (const float*)d_in[0];
    const float* gamma  = (const float*)d_in[1];
    const float* beta   = (const float*)d_in[2];
    const float* qkv_w  = (const float*)d_in[3];
    const float* qkv_b  = (const float*)d_in[4];
    const float* proj_w = (const float*)d_in[5];
    const float* proj_b = (const float*)d_in[6];
    float* out = (float*)d_out;

    char* wsb = (char*)d_ws;
    float* partial = (float*)wsb;                                   // 512 f32
    u16* Wq    = (u16*)(wsb + 4096);                                // 49,152 u16
    u16* Wp    = Wq + 16 * 384 * 8;                                 // 16,384 u16
    u16* qkvp  = Wp + 16 * 128 * 8;                                 // 7,077,888 u16 (24 planes)
    u16* attnp = qkvp + (size_t)BATCH * 24 * HWSZ * HD;             // 2,359,296 u16

    gn_wpack<<<288, 256, 0, stream>>>(x, partial, qkv_w, proj_w, Wq, Wp);

    qkv_fused<<<432, 256, 0, stream>>>(x, partial, gamma, beta, Wq, qkv_b, qkvp);

    natten_mfma<<<dim3(32, HEADS, BATCH), 384, 0, stream>>>(qkvp, attnp);

    proj_gemm<<<288, 256, 0, stream>>>(Wp, attnp, proj_b, out);
}

// Round 11
// 41.312 us; speedup vs baseline: 1.0351x; 1.0351x over previous
//
#include <hip/hip_runtime.h>
#include <hip/hip_bf16.h>

typedef unsigned short u16;
typedef unsigned int   u32;
typedef __attribute__((ext_vector_type(8))) short short8;
typedef __attribute__((ext_vector_type(4))) float f32x4;

#define BATCH 2
#define CCH   128
#define HH    96
#define WW    96
#define HWSZ  9216
#define HEADS 8
#define HD    16
#define GROUPS 32
#define EPSV  1e-6f

// fp32 -> bf16 RNE via hardware convert
static __device__ __forceinline__ u16 f2bf(float f) {
    return __builtin_bit_cast(u16, (__bf16)f);
}
static __device__ __forceinline__ u32 pk2(float a, float b) {
    return (u32)f2bf(a) | ((u32)f2bf(b) << 16);
}
static __device__ __forceinline__ short8 mk8(u32 a, u32 b, u32 c, u32 d) {
    union { short8 v; u32 w[4]; } u; u.w[0]=a; u.w[1]=b; u.w[2]=c; u.w[3]=d; return u.v;
}

// ---------------------------------------------------------------------------
// Fused: GN partial stats (blocks 0..511, one EIGHTH of a (b,g) group each:
// 4608 floats) + weight packing (blocks 512..543).
// partial[2*bq8]=sum, [2*bq8+1]=sumsq, bq8=(b*32+g)*8+e.
// ---------------------------------------------------------------------------
__global__ __launch_bounds__(256) void gn_wpack(const float* __restrict__ x,
                                                float* __restrict__ partial,
                                                const float* __restrict__ qkv_w,
                                                const float* __restrict__ proj_w,
                                                u16* __restrict__ Wq, u16* __restrict__ Wp) {
    if (blockIdx.x < 512) {
        const int bq = blockIdx.x;
        const float4* base = (const float4*)(x + (size_t)bq * 4608);
        float s = 0.f, ss = 0.f;
        for (int i = threadIdx.x; i < 1152; i += 256) {
            float4 v = base[i];
            s  += v.x + v.y + v.z + v.w;
            ss += v.x * v.x + v.y * v.y + v.z * v.z + v.w * v.w;
        }
        #pragma unroll
        for (int off = 32; off > 0; off >>= 1) {
            s  += __shfl_down(s, off);
            ss += __shfl_down(ss, off);
        }
        __shared__ float rs[4], rss[4];
        const int wid = threadIdx.x >> 6, lane = threadIdx.x & 63;
        if (lane == 0) { rs[wid] = s; rss[wid] = ss; }
        __syncthreads();
        if (threadIdx.x == 0) {
            partial[2 * bq]     = rs[0] + rs[1] + rs[2] + rs[3];
            partial[2 * bq + 1] = rss[0] + rss[1] + rss[2] + rss[3];
        }
    } else {
        const int t = (blockIdx.x - 512) * 256 + threadIdx.x;
        if (t < 16 * 384) {
            int cb = t / 384, o = t % 384;
            u16 pk[8];
            #pragma unroll
            for (int j = 0; j < 8; ++j) pk[j] = f2bf(qkv_w[o * 128 + cb * 8 + j]);
            uint4 r;
            r.x = (u32)pk[0] | ((u32)pk[1] << 16); r.y = (u32)pk[2] | ((u32)pk[3] << 16);
            r.z = (u32)pk[4] | ((u32)pk[5] << 16); r.w = (u32)pk[6] | ((u32)pk[7] << 16);
            *(uint4*)(Wq + (size_t)t * 8) = r;
        } else if (t < 16 * 384 + 16 * 128) {
            int i = t - 16 * 384;
            int cb = i / 128, o = i % 128;
            u16 pk[8];
            #pragma unroll
            for (int j = 0; j < 8; ++j) pk[j] = f2bf(proj_w[o * 128 + cb * 8 + j]);
            uint4 r;
            r.x = (u32)pk[0] | ((u32)pk[1] << 16); r.y = (u32)pk[2] | ((u32)pk[3] << 16);
            r.z = (u32)pk[4] | ((u32)pk[5] << 16); r.w = (u32)pk[6] | ((u32)pk[7] << 16);
            *(uint4*)(Wp + (size_t)i * 8) = r;
        }
    }
}

// ---------------------------------------------------------------------------
// QKV GEMM fused with GroupNorm-normalize staging. 64-px tiles -> 864 blocks,
// 17.3 KB LDS -> ~8 blocks/CU (full occupancy). XCD-chunk swizzled so the 3
// ot-blocks sharing one x-tile land on one XCD.
// ---------------------------------------------------------------------------
__global__ __launch_bounds__(256) void qkv_fused(const float* __restrict__ x,
                                                 const float* __restrict__ partial,
                                                 const float* __restrict__ gamma,
                                                 const float* __restrict__ beta,
                                                 const u16* __restrict__ Wq,
                                                 const float* __restrict__ qkv_b,
                                                 u16* __restrict__ qkvp) {
    __shared__ float scale[CCH], shift[CCH];
    __shared__ u16 Xt[16 * 64 * 8];   // 16 KB
    const int t = threadIdx.x;
    const int pph = blockIdx.x;                   // 0..863
    const int L = (pph & 7) * 108 + (pph >> 3);   // chunk swizzle (864 = 8*108)
    const int b = L / 432;
    const int r = L % 432;
    const int pt = r / 3, ot = r % 3;             // pt: 64-px tile 0..143

    if (t < CCH) {
        const int c = t, g = c >> 2, bg = b * GROUPS + g;
        float S = 0.f, SS = 0.f;
        #pragma unroll
        for (int e = 0; e < 8; ++e) {
            S  += partial[2 * (bg * 8 + e)];
            SS += partial[2 * (bg * 8 + e) + 1];
        }
        const float mean = S * (1.f / 36864.f);
        const float rstd = rsqrtf(SS * (1.f / 36864.f) - mean * mean + EPSV);
        const float sc = rstd * gamma[c];
        scale[c] = sc;
        shift[c] = beta[c] - mean * sc;
    }
    __syncthreads();

    {
        const int px = t & 63, chh = t >> 6;     // 4 channel-groups of 4 cb
        const float* xb = x + (size_t)b * CCH * HWSZ + (size_t)pt * 64 + px;
        #pragma unroll
        for (int cbi = 0; cbi < 4; ++cbi) {
            const int cb = chh * 4 + cbi;
            u16 pk[8];
            #pragma unroll
            for (int j = 0; j < 8; ++j) {
                const int c = cb * 8 + j;
                pk[j] = f2bf(__builtin_fmaf(xb[(size_t)c * HWSZ], scale[c], shift[c]));
            }
            uint4 o;
            o.x = (u32)pk[0] | ((u32)pk[1] << 16);
            o.y = (u32)pk[2] | ((u32)pk[3] << 16);
            o.z = (u32)pk[4] | ((u32)pk[5] << 16);
            o.w = (u32)pk[6] | ((u32)pk[7] << 16);
            *(uint4*)&Xt[((size_t)cb * 64 + px) * 8] = o;
        }
    }
    __syncthreads();

    const int l = t & 63, w = t >> 6;
    const int OB = ot * 128 + (w & 1) * 64;
    const int PL = (w >> 1) * 32;
    const int q = l >> 4, lo = l & 15;

    float bv[4][4];
    #pragma unroll
    for (int of = 0; of < 4; ++of)
        #pragma unroll
        for (int r2 = 0; r2 < 4; ++r2) bv[of][r2] = qkv_b[OB + of * 16 + q * 4 + r2];

    f32x4 acc[4][2] = {};
    #pragma unroll
    for (int ks = 0; ks < 4; ++ks) {
        const int cb = ks * 4 + q;
        short8 a[4];
        #pragma unroll
        for (int of = 0; of < 4; ++of)
            a[of] = *(const short8*)(Wq + ((size_t)cb * 384 + OB + of * 16 + lo) * 8);
        #pragma unroll
        for (int pf = 0; pf < 2; ++pf) {
            short8 bb = *(const short8*)&Xt[((size_t)cb * 64 + PL + pf * 16 + lo) * 8];
            #pragma unroll
            for (int of = 0; of < 4; ++of)
                acc[of][pf] = __builtin_amdgcn_mfma_f32_16x16x32_bf16(a[of], bb, acc[of][pf], 0, 0, 0);
        }
    }

    #pragma unroll
    for (int of = 0; of < 4; ++of) {
        const int plane = b * 24 + (OB >> 4) + of;
        #pragma unroll
        for (int pf = 0; pf < 2; ++pf) {
            const int p = pt * 64 + PL + pf * 16 + lo;
            uint2 pkt;
            pkt.x = pk2(acc[of][pf][0] + bv[of][0], acc[of][pf][1] + bv[of][1]);
            pkt.y = pk2(acc[of][pf][2] + bv[of][2], acc[of][pf][3] + bv[of][3]);
            *(uint2*)(qkvp + ((size_t)plane * HWSZ + p) * 16 + q * 4) = pkt;
        }
    }
}

// ---------------------------------------------------------------------------
// Proj GEMM: 32-px tiles -> 576 blocks (~9 waves/CU). Wave = 64o x 16px.
// ---------------------------------------------------------------------------
__global__ __launch_bounds__(256) void proj_gemm(const u16* __restrict__ Wpk,
                                                 const u16* __restrict__ Xpk,
                                                 const float* __restrict__ bias,
                                                 float* __restrict__ out_f32) {
    const int bid = blockIdx.x;              // 0..575
    const int b = bid / 288, pt = bid % 288;
    const int l = threadIdx.x & 63, w = threadIdx.x >> 6;
    const int OB = (w & 1) * 64;
    const int PB = pt * 32 + (w >> 1) * 16;
    const int q = l >> 4, lo = l & 15;
    const u16* Xb = Xpk + (size_t)b * 16 * HWSZ * 8;

    float bv[4][4];
    #pragma unroll
    for (int of = 0; of < 4; ++of)
        #pragma unroll
        for (int r = 0; r < 4; ++r) bv[of][r] = bias[OB + of * 16 + q * 4 + r];

    f32x4 acc[4] = {};
    #pragma unroll
    for (int ks = 0; ks < 4; ++ks) {
        const int cb = ks * 4 + q;
        short8 a[4];
        #pragma unroll
        for (int of = 0; of < 4; ++of)
            a[of] = *(const short8*)(Wpk + ((size_t)cb * 128 + OB + of * 16 + lo) * 8);
        short8 bb = *(const short8*)(Xb + ((size_t)cb * HWSZ + PB + lo) * 8);
        #pragma unroll
        for (int of = 0; of < 4; ++of)
            acc[of] = __builtin_amdgcn_mfma_f32_16x16x32_bf16(a[of], bb, acc[of], 0, 0, 0);
    }

    #pragma unroll
    for (int of = 0; of < 4; ++of) {
        const int p = PB + lo;
        #pragma unroll
        for (int r = 0; r < 4; ++r) {
            const int o = OB + of * 16 + q * 4 + r;
            out_f32[((size_t)(b * 128 + o)) * HWSZ + p] = acc[of][r] + bv[of][r];
        }
    }
}

// ---------------------------------------------------------------------------
// MFMA NATTEN v4 — round-9 proven version, byte-identical.
// ---------------------------------------------------------------------------
__global__ __launch_bounds__(384) void natten_mfma(const u16* __restrict__ qkv,
                                                   u16* __restrict__ attn_out) {
    __shared__ u16 Ks[13 * 64 * 16];   // 26 KB
    __shared__ u16 VsT[16 * 840];      // 26.3 KB
    const int tid = threadIdx.x;
    const int xh = blockIdx.x & 1, yb = blockIdx.x >> 1;
    const int h = blockIdx.y, b = blockIdx.z;
    const int ry0 = min(max(yb * 6 - 3, 0), 83);
    const int rx0 = xh * 32;

    for (int i = tid; i < 3328; i += 384) {
        if (i < 1664) {
            const int px = i >> 1, half = i & 1;
            const int row = px >> 6, col = px & 63;
            const u16* gp = qkv + ((size_t)(b * 24 + 8 + h) * HWSZ
                                 + (ry0 + row) * WW + rx0 + col) * 16 + half * 8;
            *(uint4*)&Ks[px * 16 + half * 8] = *(const uint4*)gp;
        } else {
            const int j2 = i - 1664;
            const int px = j2 >> 1, half = j2 & 1;
            const int row = px >> 6, col = px & 63;
            const u16* gp = qkv + ((size_t)(b * 24 + 16 + h) * HWSZ
                                 + (ry0 + row) * WW + rx0 + col) * 16 + half * 8;
            const uint4 vv = *(const uint4*)gp;
            const int ch0 = half * 8;
            VsT[(ch0 + 0) * 840 + px] = (u16)(vv.x);
            VsT[(ch0 + 1) * 840 + px] = (u16)(vv.x >> 16);
            VsT[(ch0 + 2) * 840 + px] = (u16)(vv.y);
            VsT[(ch0 + 3) * 840 + px] = (u16)(vv.y >> 16);
            VsT[(ch0 + 4) * 840 + px] = (u16)(vv.z);
            VsT[(ch0 + 5) * 840 + px] = (u16)(vv.z >> 16);
            VsT[(ch0 + 6) * 840 + px] = (u16)(vv.w);
            VsT[(ch0 + 7) * 840 + px] = (u16)(vv.w >> 16);
        }
    }
    __syncthreads();

    const int l = tid & 63, wv = tid >> 6;
    const int m = l & 15, q4 = l >> 4;
    const int yq = m >> 3, xq = m & 7;

    for (int j = 0; j < 3; ++j) {
        const int g = wv * 3 + j;
        const int gy = g / 6, gx = g % 6;
        const int y0g = yb * 6 + gy * 2, x0g = xh * 48 + gx * 8;
        const int yabs = y0g + yq, xabs = x0g + xq;
        const int sy = min(max(yabs - 3, 0), 88);
        const int sx = min(max(xabs - 3, 0), 88);
        const int dy0 = min(max(y0g - 3, 0), 88) - ry0;
        const int rd0 = dy0 - (sy - ry0);
        const int cx0 = (min(max(x0g - 3 - rx0, 0), 48)) & ~3;
        const int cd0 = cx0 + q4 * 4 - (sx - rx0);
        const int qpix = yabs * WW + xabs;

        const uint2 qw = *(const uint2*)(qkv + ((size_t)(b * 24 + h) * HWSZ + qpix) * 16 + q4 * 4);
        const short8 qb = mk8(qw.x, qw.y, 0u, 0u);

        const float NEGB = -1e30f;
        float colb[4];
        #pragma unroll
        for (int r = 0; r < 4; ++r) colb[r] = ((u32)(cd0 + r) < 8u) ? 0.f : NEGB;

        float ev[9][4];
        float vs = 0.f;
        #pragma unroll
        for (int t = 0; t < 9; ++t) {
            const int trow = min(dy0 + t, 12);
            const uint2 kk = *(const uint2*)&Ks[(trow * 64 + cx0 + m) * 16 + q4 * 4];
            f32x4 lg = __builtin_amdgcn_mfma_f32_16x16x32_bf16(
                mk8(kk.x, kk.y, kk.x, kk.y), qb, (f32x4){0.f, 0.f, 0.f, 0.f}, 0, 0, 0);
            const float rb = ((u32)(t + rd0) < 8u) ? 0.f : NEGB;
            #pragma unroll
            for (int r = 0; r < 4; ++r) {
                const float e = __expf(__builtin_fmaf(lg[r], 0.25f, colb[r] + rb));
                ev[t][r] = e;
                vs += e;
            }
        }
        vs += __shfl_xor(vs, 16);
        vs += __shfl_xor(vs, 32);
        const float inv = 1.0f / vs;

        u32 pd0[9], pd1[9];
        #pragma unroll
        for (int t = 0; t < 9; ++t) {
            pd0[t] = pk2(ev[t][0], ev[t][1]);
            pd1[t] = pk2(ev[t][2], ev[t][3]);
        }

        f32x4 acc = {};
        #pragma unroll
        for (int t = 0; t < 9; ++t) {
            const int trow = min(dy0 + t, 12);
            const uint2 va = *(const uint2*)&VsT[m * 840 + trow * 64 + cx0 + q4 * 4];
            acc = __builtin_amdgcn_mfma_f32_16x16x32_bf16(
                mk8(va.x, va.y, va.x, va.y), mk8(pd0[t], pd1[t], 0u, 0u), acc, 0, 0, 0);
        }

        uint2 od;
        od.x = pk2(acc[0] * inv, acc[1] * inv);
        od.y = pk2(acc[2] * inv, acc[3] * inv);
        *(uint2*)(attn_out + ((size_t)(b * 16 + h * 2 + (q4 >> 1)) * HWSZ + qpix) * 8
                  + (q4 & 1) * 4) = od;
    }
}

// ---------------------------------------------------------------------------
extern "C" void kernel_launch(void* const* d_in, const int* in_sizes, int n_in,
                              void* d_out, int out_size, void* d_ws, size_t ws_size,
                              hipStream_t stream) {
    const float* x      = (const float*)d_in[0];
    const float* gamma  = (const float*)d_in[1];
    const float* beta   = (const float*)d_in[2];
    const float* qkv_w  = (const float*)d_in[3];
    const float* qkv_b  = (const float*)d_in[4];
    const float* proj_w = (const float*)d_in[5];
    const float* proj_b = (const float*)d_in[6];
    float* out = (float*)d_out;

    char* wsb = (char*)d_ws;
    float* partial = (float*)wsb;                                   // 1024 f32
    u16* Wq    = (u16*)(wsb + 8192);                                // 49,152 u16
    u16* Wp    = Wq + 16 * 384 * 8;                                 // 16,384 u16
    u16* qkvp  = Wp + 16 * 128 * 8;                                 // 7,077,888 u16 (24 planes)
    u16* attnp = qkvp + (size_t)BATCH * 24 * HWSZ * HD;             // 2,359,296 u16

    gn_wpack<<<544, 256, 0, stream>>>(x, partial, qkv_w, proj_w, Wq, Wp);

    qkv_fused<<<864, 256, 0, stream>>>(x, partial, gamma, beta, Wq, qkv_b, qkvp);

    natten_mfma<<<dim3(32, HEADS, BATCH), 384, 0, stream>>>(qkvp, attnp);

    proj_gemm<<<576, 256, 0, stream>>>(Wp, attnp, proj_b, out);
}